// Round 1
// baseline (58.373 us; speedup 1.0000x reference)
//
#include <hip/hip_runtime.h>

#define NB 8
#define SS 2048
#define DD 128
#define SCALE 0.35355339059327373f

typedef _Float16 f16x8 __attribute__((ext_vector_type(8)));
typedef float f32x16 __attribute__((ext_vector_type(16)));
typedef unsigned short u16;
typedef u16 u16x8 __attribute__((ext_vector_type(8)));

__device__ __forceinline__ unsigned pkrtz(float a, float b) {
    unsigned w;
    asm("v_cvt_pkrtz_f16_f32 %0, %1, %2" : "=v"(w) : "v"(a), "v"(b));
    return w;
}

// ---------------- Kernel 1: U = quantum_measure(x, theta), stored f16 ----------------
__global__ __launch_bounds__(256) void qmeasure_kernel(const float* __restrict__ x,
                                                       const float* __restrict__ theta,
                                                       u16* __restrict__ U, int n) {
    int idx = blockIdx.x * 256 + threadIdx.x;
    if (idx >= n) return;
    const float4* xp = (const float4*)(x + (size_t)idx * 8);
    float4 a = xp[0], b = xp[1];
    float c[8];
    c[0] = __cosf(a.x + theta[0]); c[1] = __cosf(a.y + theta[1]);
    c[2] = __cosf(a.z + theta[2]); c[3] = __cosf(a.w + theta[3]);
    c[4] = __cosf(b.x + theta[4]); c[5] = __cosf(b.y + theta[5]);
    c[6] = __cosf(b.z + theta[6]); c[7] = __cosf(b.w + theta[7]);
    float o[8];
    o[1] = c[0] * c[1];
    o[2] = o[1] * c[2]; o[3] = o[2] * c[3]; o[4] = o[3] * c[4];
    o[5] = o[4] * c[5]; o[6] = o[5] * c[6]; o[7] = o[6] * c[7];
    float z = c[1] * c[2]; z *= c[3]; z *= c[4]; z *= c[5]; z *= c[6]; z *= c[7];
    o[0] = z;
    u16x8 w;
#pragma unroll
    for (int i = 0; i < 8; ++i) w[i] = __builtin_bit_cast(u16, (_Float16)o[i]);
    *(u16x8*)(U + (size_t)idx * 8) = w;
}

// ---------------- Kernel 2: flash attention, Q=K=V=U ----------------
// grid 256 = 8 batches x 32 q-blocks (b = bid&7 for XCD locality). 4 waves/WG.
// wave w: pair = w>>1 (kv split even/odd tiles), wq = w&1 (q sub-block of 32 rows).
// Swapped QK^T: S^T = K·Q^T via mfma_f32_32x32x16_f16; lane owns q-col = lane&31.
// O^T = V^T·P^T so rescale/normalize use lane-local (m,l).
__global__ __launch_bounds__(256, 1) void qattn_kernel(const u16* __restrict__ U,
                                                       float* __restrict__ out) {
    __shared__ __align__(16) unsigned char smem[65536];
    u16* Kt = (u16*)smem;             // [2][64][128] f16, swizzled: chunk16B ^= (row&15)
    u16* Vt = (u16*)(smem + 32768);   // [2][128][64] f16 (V^T), swizzled: chunk16B ^= (d&7)

    const int tid = threadIdx.x;
    const int lane = tid & 63;
    const int wave = tid >> 6;
    const int lo5 = lane & 31;
    const int hi = lane >> 5;
    const int pair = wave >> 1;
    const int wq = wave & 1;
    const int bid = blockIdx.x;
    const int b = bid & 7;
    const int qblk = bid >> 3;
    const u16* Ub = U + (size_t)b * SS * DD;
    const int qbase = qblk * 64 + wq * 32;

    // Q fragments (B-operand layout: B[k][j]: j=lo5 -> q row, k = hi*8+u within 16-slice)
    f16x8 qf[8];
    {
        const u16* qp = Ub + (size_t)(qbase + lo5) * DD + hi * 8;
#pragma unroll
        for (int kc = 0; kc < 8; ++kc) qf[kc] = *(const f16x8*)(qp + kc * 16);
    }

    f32x16 accT[4];
#pragma unroll
    for (int dt = 0; dt < 4; ++dt)
#pragma unroll
        for (int e = 0; e < 16; ++e) accT[dt][e] = 0.f;
    float m = -3.0e38f, l = 0.f;

    const int r2 = tid & 31;   // row-pair id for staging
    const int cb = tid >> 5;   // chunk base 0..7

    for (int it = 0; it < 16; ++it) {
        __syncthreads();
        // ---- stage tiles 2*it -> buf0, 2*it+1 -> buf1 (K row-major + V^T) ----
#pragma unroll
        for (int tb = 0; tb < 2; ++tb) {
            const u16* src = Ub + (size_t)(2 * it + tb) * 64 * DD;
            u16* Kb = Kt + tb * (64 * 128);
            u16* Vb = Vt + tb * (128 * 64);
#pragma unroll
            for (int j = 0; j < 2; ++j) {
                const int c = cb + j * 8;          // 16B chunk 0..15
                const int ra = 2 * r2, rb = 2 * r2 + 1;
                u16x8 v0 = *(const u16x8*)(src + ra * DD + c * 8);
                u16x8 v1 = *(const u16x8*)(src + rb * DD + c * 8);
                *(u16x8*)(Kb + ra * 128 + ((c ^ (ra & 15)) * 8)) = v0;
                *(u16x8*)(Kb + rb * 128 + ((c ^ (rb & 15)) * 8)) = v1;
                const int ch3 = ra >> 3;          // kv chunk (8 wide)
                const int kvo = ra & 7;           // even
#pragma unroll
                for (int e = 0; e < 8; ++e) {
                    const int d = c * 8 + e;
                    unsigned pw = (unsigned)v0[e] | ((unsigned)v1[e] << 16);
                    *(unsigned*)(Vb + d * 64 + ((ch3 ^ (d & 7)) * 8 + kvo)) = pw;
                }
            }
        }
        __syncthreads();

        const u16* Kb = Kt + pair * (64 * 128);
        const u16* Vb = Vt + pair * (128 * 64);

        // ---- S^T = K · Q^T  (A = K rows -> kv, B = Q) ----
        f32x16 accs[2];
#pragma unroll
        for (int s = 0; s < 2; ++s) {
            f32x16 a;
#pragma unroll
            for (int e = 0; e < 16; ++e) a[e] = 0.f;
            const int row = s * 32 + lo5;
            const u16* kp = Kb + row * 128;
            const int rx = row & 15;
#pragma unroll
            for (int kc = 0; kc < 8; ++kc) {
                f16x8 kf = *(const f16x8*)(kp + (((kc * 2 + hi) ^ rx) * 8));
                a = __builtin_amdgcn_mfma_f32_32x32x16_f16(kf, qf[kc], a, 0, 0, 0);
            }
            accs[s] = a;
        }

        // ---- online softmax; lane's q = lo5, partner lane (^32) shares q ----
        float tmax = accs[0][0];
#pragma unroll
        for (int s = 0; s < 2; ++s)
#pragma unroll
            for (int r = 0; r < 16; ++r) tmax = fmaxf(tmax, accs[s][r]);
        tmax *= SCALE;
        tmax = fmaxf(tmax, __shfl_xor(tmax, 32));
        const float mnew = fmaxf(m, tmax);
        float rowsum = 0.f;
#pragma unroll
        for (int s = 0; s < 2; ++s)
#pragma unroll
            for (int r = 0; r < 16; ++r) {
                float p = __expf(accs[s][r] * SCALE - mnew);
                accs[s][r] = p;
                rowsum += p;
            }
        rowsum += __shfl_xor(rowsum, 32);
        if (!__all(mnew == m)) {
            const float corr = __expf(m - mnew);
            l = l * corr + rowsum;
#pragma unroll
            for (int dt = 0; dt < 4; ++dt)
#pragma unroll
                for (int e = 0; e < 16; ++e) accT[dt][e] *= corr;
        } else {
            l += rowsum;
        }
        m = mnew;

        // ---- build P^T fragments (B-operand): word t = kv pair (16k + 8hi + 2t) ----
        f16x8 pa[4];
#pragma unroll
        for (int kp4 = 0; kp4 < 4; ++kp4) {
            const int s = kp4 >> 1, r0 = (kp4 & 1) * 8;
            unsigned w0 = pkrtz(accs[s][r0 + 0], accs[s][r0 + 1]);
            unsigned w2 = pkrtz(accs[s][r0 + 4], accs[s][r0 + 5]);
            asm("v_permlane32_swap_b32 %0, %1" : "+v"(w0), "+v"(w2));
            unsigned w1 = pkrtz(accs[s][r0 + 2], accs[s][r0 + 3]);
            unsigned w3 = pkrtz(accs[s][r0 + 6], accs[s][r0 + 7]);
            asm("v_permlane32_swap_b32 %0, %1" : "+v"(w1), "+v"(w3));
            union { unsigned w[4]; f16x8 v; } u;
            u.w[0] = w0; u.w[1] = w1; u.w[2] = w2; u.w[3] = w3;
            pa[kp4] = u.v;
        }

        // ---- O^T += V^T · P^T  (A = V^T rows -> d, B = pa) ----
#pragma unroll
        for (int dt = 0; dt < 4; ++dt) {
            const int dd = dt * 32 + lo5;
            const u16* vp = Vb + dd * 64;
            const int dx = dd & 7;
            f32x16 a = accT[dt];
#pragma unroll
            for (int kp4 = 0; kp4 < 4; ++kp4) {
                f16x8 vf = *(const f16x8*)(vp + (((kp4 * 2 + hi) ^ dx) * 8));
                a = __builtin_amdgcn_mfma_f32_32x32x16_f16(vf, pa[kp4], a, 0, 0, 0);
            }
            accT[dt] = a;
        }
    }

    // ---- merge pair 1 into pair 0 via LDS (staging buffers are dead) ----
    __syncthreads();
    float* obuf = (float*)smem;                   // [2][4096]
    float* mbuf = (float*)(smem + 32768);         // [2][32]
    float* lbuf = (float*)(smem + 32768 + 256);   // [2][32]
    if (pair == 1) {
        if (hi == 0) { mbuf[wq * 32 + lo5] = m; lbuf[wq * 32 + lo5] = l; }
#pragma unroll
        for (int dt = 0; dt < 4; ++dt)
#pragma unroll
            for (int r = 0; r < 16; ++r)
                obuf[wq * 4096 + (dt * 16 + r) * 64 + lane] = accT[dt][r];
    }
    __syncthreads();
    if (pair == 0) {
        const float m2 = mbuf[wq * 32 + lo5];
        const float l2 = lbuf[wq * 32 + lo5];
        const float mf = fmaxf(m, m2);
        const float a1 = __expf(m - mf);
        const float a2 = __expf(m2 - mf);
        const float inv = 1.f / (l * a1 + l2 * a2);
        float* orow = out + ((size_t)b * SS + qbase + lo5) * DD;
#pragma unroll
        for (int dt = 0; dt < 4; ++dt)
#pragma unroll
            for (int r = 0; r < 16; ++r) {
                const int drow = (r & 3) + 8 * (r >> 2) + 4 * hi;
                const float o = (accT[dt][r] * a1 +
                                 obuf[wq * 4096 + (dt * 16 + r) * 64 + lane] * a2) * inv;
                orow[dt * 32 + drow] = o;
            }
    }
}

extern "C" void kernel_launch(void* const* d_in, const int* in_sizes, int n_in,
                              void* d_out, int out_size, void* d_ws, size_t ws_size,
                              hipStream_t stream) {
    const float* x = (const float*)d_in[0];
    const float* theta = (const float*)d_in[1];
    float* outp = (float*)d_out;
    u16* U = (u16*)d_ws;   // 8*2048*128 f16 = 4 MB

    const int ngroups = NB * SS * (DD / 8);  // 262144
    qmeasure_kernel<<<ngroups / 256, 256, 0, stream>>>(x, theta, U, ngroups);
    qattn_kernel<<<256, 256, 0, stream>>>(U, outp);
}

// Round 2
// 36.029 us; speedup vs baseline: 1.6202x; 1.6202x over previous
//
#include <hip/hip_runtime.h>

#define NB 8
#define SS 2048
#define DD 128
#define SCALE 0.35355339059327373f

typedef _Float16 f16x8 __attribute__((ext_vector_type(8)));
typedef float f32x16 __attribute__((ext_vector_type(16)));
typedef unsigned short u16;
typedef u16 u16x8 __attribute__((ext_vector_type(8)));

__device__ __forceinline__ unsigned pkrtz(float a, float b) {
    unsigned w;
    asm("v_cvt_pkrtz_f16_f32 %0, %1, %2" : "=v"(w) : "v"(a), "v"(b));
    return w;
}

// ---------------- Kernel 1: U = quantum_measure(x, theta) ----------------
// Emits TWO fragment-order f16 layouts (per batch, per 32-row s-tile t):
//  G1 : chunk16B[t*512 + kc*64 + hi*32 + r]  holds U[t*32+r][kc*16+hi*8 + 0..7]
//       (serves Q B-frags and K A-frags: addr = base + t*8192B + kc*1024B + lane*16B)
//  G2t: chunk16B[t*512 + (dt*2+kc2)*64 + hi*32 + lo5] holds U[t*32+kc2*16+hi*8+u][dt*32+lo5]
//       (serves V^T A-frags: addr = base + t*8192B + j*1024B + lane*16B, j=dt*2+kc2)
__global__ __launch_bounds__(512) void qmeasure_kernel(const float* __restrict__ x,
                                                       const float* __restrict__ theta,
                                                       u16* __restrict__ G1,
                                                       u16* __restrict__ G2) {
    __shared__ u16 olds[32][128];
    const int bid = blockIdx.x;
    const int b = bid & 7;
    const int t = bid >> 3;
    const int tid = threadIdx.x;
    const int s = tid >> 4;     // 0..31
    const int c = tid & 15;     // 16B chunk (head) index 0..15

    float th[8];
    *(float4*)th = *(const float4*)theta;
    *(float4*)(th + 4) = *(const float4*)(theta + 4);

    const float* xp = x + (((size_t)b * SS + t * 32 + s) * DD) + c * 8;
    float4 a = *(const float4*)xp;
    float4 a2 = *(const float4*)(xp + 4);
    float cc[8];
    cc[0] = __cosf(a.x + th[0]);  cc[1] = __cosf(a.y + th[1]);
    cc[2] = __cosf(a.z + th[2]);  cc[3] = __cosf(a.w + th[3]);
    cc[4] = __cosf(a2.x + th[4]); cc[5] = __cosf(a2.y + th[5]);
    cc[6] = __cosf(a2.z + th[6]); cc[7] = __cosf(a2.w + th[7]);
    float o[8];
    o[1] = cc[0] * cc[1];
    o[2] = o[1] * cc[2]; o[3] = o[2] * cc[3]; o[4] = o[3] * cc[4];
    o[5] = o[4] * cc[5]; o[6] = o[5] * cc[6]; o[7] = o[6] * cc[7];
    float z = cc[1] * cc[2]; z *= cc[3]; z *= cc[4]; z *= cc[5]; z *= cc[6]; z *= cc[7];
    o[0] = z;

    u16x8 w;
#pragma unroll
    for (int e = 0; e < 8; ++e) w[e] = __builtin_bit_cast(u16, (_Float16)o[e]);

    // G1 store
    {
        const int chunk = t * 512 + (c >> 1) * 64 + (c & 1) * 32 + s;
        *(u16x8*)(G1 + (size_t)b * (SS * DD) + (size_t)chunk * 8) = w;
    }
    // LDS tile for the transpose
    *(u16x8*)&olds[s][c * 8] = w;
    __syncthreads();

    // G2t store: thread = chunk m = tid
    {
        const int lo5 = tid & 31;
        const int hi = (tid >> 5) & 1;
        const int dkc = tid >> 6;          // 0..7 = dt*2+kc2
        const int dt = dkc >> 1, kc2 = dkc & 1;
        u16x8 g;
#pragma unroll
        for (int u = 0; u < 8; ++u) g[u] = olds[kc2 * 16 + hi * 8 + u][dt * 32 + lo5];
        const int chunk = t * 512 + dkc * 64 + hi * 32 + lo5;
        *(u16x8*)(G2 + (size_t)b * (SS * DD) + (size_t)chunk * 8) = g;
    }
}

// ---------------- Kernel 2: flash attention, Q=K=V, LDS-free main loop ----------------
// grid 256 = 8 batches (bid&7, XCD-pinned) x 32 q-groups of 64 rows.
// block 512 thr = 8 waves: qw = wave&1 (32 q rows), kq = wave>>2? no: kq = wave>>1 (KV quarter).
// Per wave: swapped QK^T (S^T = K.Q^T), lane owns q = lane&31; online softmax with defer-max;
// O^T = V^T.P^T with V^T frags from G2t. 4-way KV merge via LDS at the end (2 dt-rounds).
__global__ __launch_bounds__(512, 2) void qattn_kernel(const u16* __restrict__ G1g,
                                                       const u16* __restrict__ G2g,
                                                       float* __restrict__ out) {
    __shared__ float obuf[2][3][2][16][64];   // 48 KB
    __shared__ float mlb[2][3][2][32];        // 1.5 KB

    const int tid = threadIdx.x;
    const int lane = tid & 63;
    const int wave = tid >> 6;
    const int lo5 = lane & 31;
    const int hi = lane >> 5;
    const int qw = wave & 1;
    const int kq = wave >> 1;    // KV quarter 0..3
    const int bid = blockIdx.x;
    const int b = bid & 7;
    const int qg = bid >> 3;     // 0..31

    const u16* G1b = G1g + (size_t)b * (SS * DD);
    const u16* G2b = G2g + (size_t)b * (SS * DD);

    // Q fragments (B-operand): q-tile tq = qg*2+qw
    f16x8 qf[8];
    {
        const u16* qp = G1b + (size_t)(qg * 2 + qw) * 4096 + lane * 8;
#pragma unroll
        for (int kc = 0; kc < 8; ++kc) qf[kc] = *(const f16x8*)(qp + kc * 512);
    }

    f32x16 accT[4];
#pragma unroll
    for (int dt = 0; dt < 4; ++dt)
#pragma unroll
        for (int e = 0; e < 16; ++e) accT[dt][e] = 0.f;
    float m = -3.0e38f, l = 0.f;

    for (int it = 0; it < 16; ++it) {
        const int t = kq * 16 + it;

        // K A-frags (coalesced, L2-resident)
        const u16* kp = G1b + (size_t)t * 4096 + lane * 8;
        f16x8 kf[8];
#pragma unroll
        for (int kc = 0; kc < 8; ++kc) kf[kc] = *(const f16x8*)(kp + kc * 512);

        // S^T = K . Q^T
        f32x16 acc;
#pragma unroll
        for (int e = 0; e < 16; ++e) acc[e] = 0.f;
#pragma unroll
        for (int kc = 0; kc < 8; ++kc)
            acc = __builtin_amdgcn_mfma_f32_32x32x16_f16(kf[kc], qf[kc], acc, 0, 0, 0);

        // V^T A-frags: issue early so latency hides under softmax
        const u16* vp = G2b + (size_t)t * 4096 + lane * 8;
        f16x8 vf[8];
#pragma unroll
        for (int j = 0; j < 8; ++j) vf[j] = *(const f16x8*)(vp + j * 512);

        // online softmax (16 kv vals/lane, partner lane ^32 shares q)
        float tmax = acc[0];
#pragma unroll
        for (int r = 1; r < 16; ++r) tmax = fmaxf(tmax, acc[r]);
        tmax *= SCALE;
        tmax = fmaxf(tmax, __shfl_xor(tmax, 32));
        if (!__all(tmax <= m + 8.f)) {         // defer-max (THR=8)
            const float mnew = fmaxf(m, tmax);
            const float corr = __expf(m - mnew);
            l *= corr;
#pragma unroll
            for (int dt = 0; dt < 4; ++dt)
#pragma unroll
                for (int e = 0; e < 16; ++e) accT[dt][e] *= corr;
            m = mnew;
        }
        float rowsum = 0.f;
#pragma unroll
        for (int r = 0; r < 16; ++r) {
            float p = __expf(acc[r] * SCALE - m);
            acc[r] = p;
            rowsum += p;
        }
        rowsum += __shfl_xor(rowsum, 32);
        l += rowsum;

        // P^T B-frags (2): elems = kv 16*kc2+8*hi+u
        f16x8 pa[2];
#pragma unroll
        for (int kc2 = 0; kc2 < 2; ++kc2) {
            const int r0 = kc2 * 8;
            unsigned w0 = pkrtz(acc[r0 + 0], acc[r0 + 1]);
            unsigned w2 = pkrtz(acc[r0 + 4], acc[r0 + 5]);
            asm("v_permlane32_swap_b32 %0, %1" : "+v"(w0), "+v"(w2));
            unsigned w1 = pkrtz(acc[r0 + 2], acc[r0 + 3]);
            unsigned w3 = pkrtz(acc[r0 + 6], acc[r0 + 7]);
            asm("v_permlane32_swap_b32 %0, %1" : "+v"(w1), "+v"(w3));
            union { unsigned w[4]; f16x8 v; } u;
            u.w[0] = w0; u.w[1] = w1; u.w[2] = w2; u.w[3] = w3;
            pa[kc2] = u.v;
        }

        // O^T += V^T . P^T
#pragma unroll
        for (int dt = 0; dt < 4; ++dt) {
            f32x16 a = accT[dt];
#pragma unroll
            for (int kc2 = 0; kc2 < 2; ++kc2)
                a = __builtin_amdgcn_mfma_f32_32x32x16_f16(vf[dt * 2 + kc2], pa[kc2], a, 0, 0, 0);
            accT[dt] = a;
        }
    }

    // ---- 4-way KV merge (2 rounds over dt halves) ----
    __syncthreads();
    float* orow = out + ((size_t)b * SS + qg * 64 + qw * 32 + lo5) * DD;
#pragma unroll
    for (int half = 0; half < 2; ++half) {
        if (kq > 0) {
            if (half == 0 && hi == 0) {
                mlb[qw][kq - 1][0][lo5] = m;
                mlb[qw][kq - 1][1][lo5] = l;
            }
#pragma unroll
            for (int dh = 0; dh < 2; ++dh)
#pragma unroll
                for (int r = 0; r < 16; ++r)
                    obuf[qw][kq - 1][dh][r][lane] = accT[half * 2 + dh][r];
        }
        __syncthreads();
        if (kq == 0) {
            const float mj0 = mlb[qw][0][0][lo5], lj0 = mlb[qw][0][1][lo5];
            const float mj1 = mlb[qw][1][0][lo5], lj1 = mlb[qw][1][1][lo5];
            const float mj2 = mlb[qw][2][0][lo5], lj2 = mlb[qw][2][1][lo5];
            const float ms = fmaxf(fmaxf(m, mj0), fmaxf(mj1, mj2));
            const float w0 = __expf(m - ms), w1 = __expf(mj0 - ms);
            const float w2 = __expf(mj1 - ms), w3 = __expf(mj2 - ms);
            const float linv = 1.f / (l * w0 + lj0 * w1 + lj1 * w2 + lj2 * w3);
#pragma unroll
            for (int dh = 0; dh < 2; ++dh) {
                const int dt = half * 2 + dh;
#pragma unroll
                for (int r = 0; r < 16; ++r) {
                    const float o = accT[dt][r] * w0 + obuf[qw][0][dh][r][lane] * w1 +
                                    obuf[qw][1][dh][r][lane] * w2 + obuf[qw][2][dh][r][lane] * w3;
                    const int drow = (r & 3) + 8 * (r >> 2) + 4 * hi;
                    orow[dt * 32 + drow] = o * linv;
                }
            }
        }
        __syncthreads();
    }
}

extern "C" void kernel_launch(void* const* d_in, const int* in_sizes, int n_in,
                              void* d_out, int out_size, void* d_ws, size_t ws_size,
                              hipStream_t stream) {
    const float* x = (const float*)d_in[0];
    const float* theta = (const float*)d_in[1];
    float* outp = (float*)d_out;
    u16* G1 = (u16*)d_ws;                       // 8*2048*128 f16 = 4 MB
    u16* G2 = G1 + (size_t)NB * SS * DD;        // +4 MB

    qmeasure_kernel<<<512, 512, 0, stream>>>(x, theta, G1, G2);
    qattn_kernel<<<256, 512, 0, stream>>>(G1, G2, outp);
}